// Round 6
// baseline (292.783 us; speedup 1.0000x reference)
//
#include <hip/hip_runtime.h>
#include <math.h>

// IN_C=3, DIM=256, OUT_C=256, N_PIECES=20, BATCH=16, SET_N=128

#if __has_builtin(__builtin_amdgcn_exp2f)
#define EXP2F(x) __builtin_amdgcn_exp2f(x)
#else
#define EXP2F(x) exp2f(x)
#endif

#define NBLK 512

__device__ __forceinline__ float pool_weight(const float* __restrict__ pw, int j)
{
    float ratio = (float)j / 127.0f;
    float idx_f = 20.0f * ratio;
    int idx = (int)idx_f;
    float frac = idx_f - (float)idx;
    int idx2 = idx + 1 > 20 ? 20 : idx + 1;
    return (1.0f - frac) * pw[idx] + frac * pw[idx2];
}

// ---------------------------------------------------------------------------
// ONE kernel: conv1+conv2 -> [grid barrier] -> fspool -> [grid barrier] -> MLP
// 512 blocks x 512 threads; <=2 blocks/CU (29 KB LDS, <=128 VGPR) so all 512
// are co-resident -> spin barrier is deadlock-free. Counters zeroed by an
// 8-byte hipMemsetAsync before each launch (graph-capturable).
// ---------------------------------------------------------------------------
__global__ __launch_bounds__(512, 4) void mega_kernel(
    const float* __restrict__ x,   const float* __restrict__ w1,
    const float* __restrict__ b1,  const float* __restrict__ W2,
    const float* __restrict__ b2,  const float* __restrict__ pool_w,
    const float* __restrict__ L1w, const float* __restrict__ L1b,
    const float* __restrict__ L2w, const float* __restrict__ L2b,
    const float* __restrict__ C1w, const float* __restrict__ C1b,
    const float* __restrict__ C2w, const float* __restrict__ C2b,
    float* __restrict__ H2, float* __restrict__ pooled,
    unsigned* __restrict__ cnt, float* __restrict__ out)
{
    __shared__ float4 xs4[64];       // (x0,x1,x2,0) per n
    __shared__ float4 w1p[256];      // (w1[k,0..2], b1[k])
    __shared__ float  As[32][17];    // W2 sub-tile, transposed, padded
    __shared__ float  Bs[32][64];    // relu(conv1)
    __shared__ float  ss[8][128];    // fspool s values (per-wave rows)
    __shared__ float2 sbp[8][128];   // (s_i, B_i*log2e)
    __shared__ float  za[256], zb[256];

    const float LOG2E = 1.4426950408889634f;
    int tid = threadIdx.x;
    int blk = blockIdx.x;

    // ================= phase 1: conv12, tile 16d x 64n =================
    {
        int bx = blk & 31;            // bn tile: b = bx>>1, n0 = (bx&1)*64
        int ti = blk >> 5;            // d tile 0..15
        int b  = bx >> 1;
        int n0 = (bx & 1) * 64;
        int d0 = ti * 16;

        if (tid < 64) {
            int n = tid;
            xs4[n] = make_float4(x[b*384 + n0 + n], x[b*384 + 128 + n0 + n],
                                 x[b*384 + 256 + n0 + n], 0.0f);
        } else if (tid < 320) {
            int k = tid - 64;
            w1p[k] = make_float4(w1[k*3], w1[k*3+1], w1[k*3+2], b1[k]);
        }
        __syncthreads();

        int tx = tid & 31, ty = tid >> 5;   // tx: n-pair, ty: d 0..15
        float acc0 = 0.f, acc1 = 0.f;

        for (int k0 = 0; k0 < 256; k0 += 32) {
            {   // stage As (coalesced global read, padded LDS write)
                int dl = tid >> 5, kk = tid & 31;
                As[kk][dl] = W2[(d0 + dl)*256 + k0 + kk];
            }
            {   // stage Bs: 4 conv1 evals per thread
                int krel = tid >> 4;
                int nl4  = (tid & 15) * 4;
                float4 w  = w1p[k0 + krel];
                float4 x0 = xs4[nl4+0], x1 = xs4[nl4+1];
                float4 x2 = xs4[nl4+2], x3 = xs4[nl4+3];
                float4 h;
                h.x = fmaxf(fmaf(w.x,x0.x, fmaf(w.y,x0.y, fmaf(w.z,x0.z, w.w))), 0.f);
                h.y = fmaxf(fmaf(w.x,x1.x, fmaf(w.y,x1.y, fmaf(w.z,x1.z, w.w))), 0.f);
                h.z = fmaxf(fmaf(w.x,x2.x, fmaf(w.y,x2.y, fmaf(w.z,x2.z, w.w))), 0.f);
                h.w = fmaxf(fmaf(w.x,x3.x, fmaf(w.y,x3.y, fmaf(w.z,x3.z, w.w))), 0.f);
                *(float4*)&Bs[krel][nl4] = h;
            }
            __syncthreads();
            #pragma unroll
            for (int kk = 0; kk < 32; kk++) {
                float  a  = As[kk][ty];
                float2 bv = *(const float2*)&Bs[kk][tx*2];
                acc0 = fmaf(a, bv.x, acc0);
                acc1 = fmaf(a, bv.y, acc1);
            }
            __syncthreads();
        }
        int d = d0 + ty;
        float bias = b2[d];
        *(float2*)(H2 + b*32768 + d*128 + n0 + tx*2) =
            make_float2(acc0 + bias, acc1 + bias);
    }

    // ================= grid barrier 1 =================
    __threadfence();
    __syncthreads();
    if (tid == 0) {
        __hip_atomic_fetch_add(&cnt[0], 1u, __ATOMIC_ACQ_REL,
                               __HIP_MEMORY_SCOPE_AGENT);
        while (__hip_atomic_load(&cnt[0], __ATOMIC_ACQUIRE,
                                 __HIP_MEMORY_SCOPE_AGENT) < (unsigned)NBLK) {}
    }
    __syncthreads();
    __threadfence();

    // ================= phase 2: fspool (wave-local rows) =================
    {
        int w = tid >> 6, l = tid & 63;
        int row = blk * 8 + w;                  // 512*8 = 4096 rows
        float2 sv = *(const float2*)(H2 + row*128 + l*2);
        *(float2*)&ss[w][l*2] = sv;             // wave-local: no barrier needed

        float si0 = ss[w][l];
        float si1 = ss[w][l + 64];
        float a0=0.f,a1=0.f,a2=0.f,a3=0.f, c0=0.f,c1=0.f,c2=0.f,c3=0.f;
        #pragma unroll 4
        for (int j = 0; j < 128; j += 4) {
            float4 s4 = *(const float4*)&ss[w][j];
            a0 += fabsf(si0 - s4.x); a1 += fabsf(si0 - s4.y);
            a2 += fabsf(si0 - s4.z); a3 += fabsf(si0 - s4.w);
            c0 += fabsf(si1 - s4.x); c1 += fabsf(si1 - s4.y);
            c2 += fabsf(si1 - s4.z); c3 += fabsf(si1 - s4.w);
        }
        sbp[w][l]      = make_float2(si0, ((a0+a1)+(a2+a3)) * LOG2E);
        sbp[w][l + 64] = make_float2(si1, ((c0+c1)+(c2+c3)) * LOG2E);

        float scal0 = (float)(127 - 2*l) * LOG2E;
        float scal1 = (float)(127 - 2*(l + 64)) * LOG2E;

        float m00=-1e30f, m01=-1e30f, m10=-1e30f, m11=-1e30f;
        #pragma unroll 4
        for (int i = 0; i < 128; i += 2) {
            float4 p = *(const float4*)&sbp[w][i];
            m00 = fmaxf(m00, fmaf(p.x, scal0, -p.y));
            m01 = fmaxf(m01, fmaf(p.z, scal0, -p.w));
            m10 = fmaxf(m10, fmaf(p.x, scal1, -p.y));
            m11 = fmaxf(m11, fmaf(p.z, scal1, -p.w));
        }
        float m0 = fmaxf(m00, m01), m1 = fmaxf(m10, m11);

        float se0a=0.f,se0b=0.f,sd0a=0.f,sd0b=0.f;
        float se1a=0.f,se1b=0.f,sd1a=0.f,sd1b=0.f;
        #pragma unroll 4
        for (int i = 0; i < 128; i += 2) {
            float4 p = *(const float4*)&sbp[w][i];
            float e0a = EXP2F(fmaf(p.x, scal0, -p.y) - m0);
            float e0b = EXP2F(fmaf(p.z, scal0, -p.w) - m0);
            float e1a = EXP2F(fmaf(p.x, scal1, -p.y) - m1);
            float e1b = EXP2F(fmaf(p.z, scal1, -p.w) - m1);
            se0a += e0a; sd0a = fmaf(e0a, p.x, sd0a);
            se0b += e0b; sd0b = fmaf(e0b, p.z, sd0b);
            se1a += e1a; sd1a = fmaf(e1a, p.x, sd1a);
            se1b += e1b; sd1b = fmaf(e1b, p.z, sd1b);
        }
        float xs0 = (sd0a + sd0b) / (se0a + se0b);
        float xs1 = (sd1a + sd1b) / (se1a + se1b);

        int c = row & 255;
        const float* pw = pool_w + c * 21;
        float part = xs0 * pool_weight(pw, l) + xs1 * pool_weight(pw, l + 64);
        #pragma unroll
        for (int off = 32; off > 0; off >>= 1)
            part += __shfl_xor(part, off);
        if (l == 0) pooled[row] = part;
    }

    // ================= grid barrier 2 (tail blocks only spin) =================
    __threadfence();
    __syncthreads();
    if (blk >= 16) {
        if (tid == 0)
            __hip_atomic_fetch_add(&cnt[1], 1u, __ATOMIC_ACQ_REL,
                                   __HIP_MEMORY_SCOPE_AGENT);
        return;
    }
    if (tid == 0) {
        __hip_atomic_fetch_add(&cnt[1], 1u, __ATOMIC_ACQ_REL,
                               __HIP_MEMORY_SCOPE_AGENT);
        while (__hip_atomic_load(&cnt[1], __ATOMIC_ACQUIRE,
                                 __HIP_MEMORY_SCOPE_AGENT) < (unsigned)NBLK) {}
    }
    __syncthreads();
    __threadfence();

    // ================= phase 3: MLP tail (blocks 0..15, b = blk) =================
    {
        int b = blk;
        if (tid < 256) za[tid] = pooled[b*256 + tid];
        __syncthreads();

        // dense512: o = tid>>1, split-K=2 (p = tid&1), shfl pair-reduce
        #pragma unroll 1
        for (int layer = 0; layer < 3; layer++) {
            const float* W  = layer == 0 ? L1w : (layer == 1 ? L2w : C1w);
            const float* Bv = layer == 0 ? L1b : (layer == 1 ? L2b : C1b);
            const float* in  = (layer & 1) ? zb : za;
            float*       o_l = (layer & 1) ? za : zb;
            bool relu = (layer != 1);
            int o = tid >> 1, p = tid & 1;
            const float* wr = W + o*256 + p*128;
            const float* ir = in + p*128;
            float acc = 0.f;
            #pragma unroll
            for (int k = 0; k < 128; k += 4) {
                float4 wv = *(const float4*)(wr + k);
                float4 iv = *(const float4*)(ir + k);
                acc = fmaf(wv.x, iv.x, acc);
                acc = fmaf(wv.y, iv.y, acc);
                acc = fmaf(wv.z, iv.z, acc);
                acc = fmaf(wv.w, iv.w, acc);
            }
            acc += __shfl_xor(acc, 1);
            if (p == 0) {
                acc += Bv[o];
                o_l[o] = relu ? fmaxf(acc, 0.f) : acc;
            }
            __syncthreads();
        }
        // cls2: 10 outputs, 32 lanes each (tid < 320), 8 k per lane
        if (tid < 320) {
            int o = tid >> 5, kb = tid & 31;
            const float* wr = C2w + o*256 + kb*8;
            const float* ir = zb + kb*8;
            float4 w0 = *(const float4*)(wr);
            float4 w1v = *(const float4*)(wr + 4);
            float4 i0 = *(const float4*)(ir);
            float4 i1 = *(const float4*)(ir + 4);
            float p = fmaf(w0.x,i0.x, fmaf(w0.y,i0.y, fmaf(w0.z,i0.z,
                      fmaf(w0.w,i0.w, fmaf(w1v.x,i1.x, fmaf(w1v.y,i1.y,
                      fmaf(w1v.z,i1.z, w1v.w*i1.w)))))));
            #pragma unroll
            for (int off = 16; off > 0; off >>= 1)
                p += __shfl_xor(p, off, 32);
            if (kb == 0) out[b*10 + o] = p + C2b[o];
        }
    }
}

// ---------------------------------------------------------------------------
extern "C" void kernel_launch(void* const* d_in, const int* in_sizes, int n_in,
                              void* d_out, int out_size, void* d_ws, size_t ws_size,
                              hipStream_t stream)
{
    (void)in_sizes; (void)n_in; (void)out_size; (void)ws_size;
    const float* x       = (const float*)d_in[0];
    const float* conv1_w = (const float*)d_in[1];
    const float* conv1_b = (const float*)d_in[2];
    const float* conv2_w = (const float*)d_in[3];
    const float* conv2_b = (const float*)d_in[4];
    const float* pool_w  = (const float*)d_in[5];
    const float* lin1_w  = (const float*)d_in[6];
    const float* lin1_b  = (const float*)d_in[7];
    const float* lin2_w  = (const float*)d_in[8];
    const float* lin2_b  = (const float*)d_in[9];
    const float* cls1_w  = (const float*)d_in[10];
    const float* cls1_b  = (const float*)d_in[11];
    const float* cls2_w  = (const float*)d_in[12];
    const float* cls2_b  = (const float*)d_in[13];
    float* out = (float*)d_out;

    float*    ws     = (float*)d_ws;
    float*    H2     = ws;                    // 524288 floats
    float*    pooled = ws + 524288;           // 4096 floats
    unsigned* cnt    = (unsigned*)(ws + 528384);  // 2 counters

    hipMemsetAsync(cnt, 0, 2 * sizeof(unsigned), stream);
    mega_kernel<<<NBLK, 512, 0, stream>>>(
        x, conv1_w, conv1_b, conv2_w, conv2_b, pool_w,
        lin1_w, lin1_b, lin2_w, lin2_b, cls1_w, cls1_b, cls2_w, cls2_b,
        H2, pooled, cnt, out);
}

// Round 7
// 85.779 us; speedup vs baseline: 3.4132x; 3.4132x over previous
//
#include <hip/hip_runtime.h>
#include <math.h>

// IN_C=3, DIM=256, OUT_C=256, N_PIECES=20, BATCH=16, SET_N=128

#if __has_builtin(__builtin_amdgcn_exp2f)
#define EXP2F(x) __builtin_amdgcn_exp2f(x)
#else
#define EXP2F(x) exp2f(x)
#endif

#define NBLK 1024

__device__ __forceinline__ float pool_weight(const float* __restrict__ pw, int j)
{
    float ratio = (float)j / 127.0f;
    float idx_f = 20.0f * ratio;
    int idx = (int)idx_f;
    float frac = idx_f - (float)idx;
    int idx2 = idx + 1 > 20 ? 20 : idx + 1;
    return (1.0f - frac) * pw[idx] + frac * pw[idx2];
}

// ---------------------------------------------------------------------------
// ONE kernel. 1024 blocks x 256 thr (4 waves). Block = (b, 4 channel rows).
// Phase 1: GEMM 4d x 128n with on-the-fly conv1 (Bsp staged per 32-k step).
//          Wave w owns row c0+w; lane l owns cols (l, l+64) -> acc0/acc1.
// Phase 2: fspool, fully wave-local in LDS (no barrier, no global H2).
// Gate:    each block atomicAdds a counter after storing its 4 pooled vals;
//          only blocks 0..15 spin (s_sleep-throttled), then run the MLP tail.
// ---------------------------------------------------------------------------
__global__ __launch_bounds__(256) void fused_all(
    const float* __restrict__ x,   const float* __restrict__ w1,
    const float* __restrict__ b1,  const float* __restrict__ W2,
    const float* __restrict__ b2,  const float* __restrict__ pool_w,
    const float* __restrict__ L1w, const float* __restrict__ L1b,
    const float* __restrict__ L2w, const float* __restrict__ L2b,
    const float* __restrict__ C1w, const float* __restrict__ C1b,
    const float* __restrict__ C2w, const float* __restrict__ C2b,
    float* __restrict__ pooled, unsigned* __restrict__ cnt,
    float* __restrict__ out)
{
    const float LOG2E = 1.4426950408889634f;
    __shared__ float4 xa4[128];      // (x0,x1,x2,0) per n            2 KB
    __shared__ float4 w1p[256];      // (w1[k,0..2], b1[k])           4 KB
    __shared__ float  Ast[4][32];    // W2 sub-tile [d-local][k]      0.5 KB
    __shared__ float2 Bsp[32][65];   // relu(conv1) pairs (n, n+64), padded 16.6 KB
    __shared__ float2 sbp[4][128];   // (s_i, B_i*log2e) per row      4 KB
    __shared__ float  za[256], zb[256]; // tail activations           2 KB

    int tid = threadIdx.x;
    int blk = blockIdx.x;
    int b   = blk >> 6;              // batch 0..15
    int c0  = (blk & 63) << 2;       // 4-row channel group

    // one-time staging
    w1p[tid] = make_float4(w1[tid*3], w1[tid*3+1], w1[tid*3+2], b1[tid]);
    if (tid < 128)
        xa4[tid] = make_float4(x[b*384 + tid], x[b*384 + 128 + tid],
                               x[b*384 + 256 + tid], 0.0f);
    __syncthreads();

    int wid = tid >> 6, l = tid & 63;
    int krel = tid & 31, p0 = (tid >> 5) * 8;   // staging map (bank-clean)
    float acc0 = 0.f, acc1 = 0.f;

    for (int k0 = 0; k0 < 256; k0 += 32) {
        if (tid < 128)
            Ast[tid >> 5][tid & 31] =
                W2[(c0 + (tid >> 5)) * 256 + k0 + (tid & 31)];
        {
            float4 wv = w1p[k0 + krel];
            #pragma unroll
            for (int i = 0; i < 8; i++) {
                int p = p0 + i;
                float4 xlo = xa4[p];
                float4 xhi = xa4[p + 64];
                float h0 = fmaf(wv.x, xlo.x, fmaf(wv.y, xlo.y,
                           fmaf(wv.z, xlo.z, wv.w)));
                float h1 = fmaf(wv.x, xhi.x, fmaf(wv.y, xhi.y,
                           fmaf(wv.z, xhi.z, wv.w)));
                Bsp[krel][p] = make_float2(fmaxf(h0, 0.f), fmaxf(h1, 0.f));
            }
        }
        __syncthreads();
        float4 a4[8];
        #pragma unroll
        for (int q = 0; q < 8; q++)
            a4[q] = *(const float4*)&Ast[wid][q * 4];
        #pragma unroll
        for (int kk = 0; kk < 32; kk++) {
            float a = ((const float*)a4)[kk];
            float2 bv = Bsp[kk][l];
            acc0 = fmaf(a, bv.x, acc0);
            acc1 = fmaf(a, bv.y, acc1);
        }
        __syncthreads();
    }

    // ---- fspool (wave-local; wave wid owns row c0+wid) ----
    float bias = b2[c0 + wid];
    float s0 = acc0 + bias, s1 = acc1 + bias;
    sbp[wid][l]      = make_float2(s0, 0.f);
    sbp[wid][l + 64] = make_float2(s1, 0.f);

    // Bsum for own i0=l, i1=l+64
    float a0 = 0.f, a1 = 0.f, g0 = 0.f, g1 = 0.f;
    #pragma unroll 8
    for (int j = 0; j < 128; j += 2) {
        float4 p = *(const float4*)&sbp[wid][j];
        a0 += fabsf(s0 - p.x); a1 += fabsf(s0 - p.z);
        g0 += fabsf(s1 - p.x); g1 += fabsf(s1 - p.z);
    }
    sbp[wid][l].y      = (a0 + a1) * LOG2E;
    sbp[wid][l + 64].y = (g0 + g1) * LOG2E;

    // softmax for j0=l, j1=l+64 (log2 domain)
    float scal0 = (float)(127 - 2 * l) * LOG2E;
    float scal1 = (float)(-1 - 2 * l) * LOG2E;
    float m00 = -1e30f, m01 = -1e30f, m10 = -1e30f, m11 = -1e30f;
    #pragma unroll 8
    for (int i = 0; i < 128; i += 2) {
        float4 p = *(const float4*)&sbp[wid][i];
        m00 = fmaxf(m00, fmaf(p.x, scal0, -p.y));
        m01 = fmaxf(m01, fmaf(p.z, scal0, -p.w));
        m10 = fmaxf(m10, fmaf(p.x, scal1, -p.y));
        m11 = fmaxf(m11, fmaf(p.z, scal1, -p.w));
    }
    float m0 = fmaxf(m00, m01), m1 = fmaxf(m10, m11);

    float se0a = 0.f, se0b = 0.f, sd0a = 0.f, sd0b = 0.f;
    float se1a = 0.f, se1b = 0.f, sd1a = 0.f, sd1b = 0.f;
    #pragma unroll 4
    for (int i = 0; i < 128; i += 2) {
        float4 p = *(const float4*)&sbp[wid][i];
        float e0a = EXP2F(fmaf(p.x, scal0, -p.y) - m0);
        float e0b = EXP2F(fmaf(p.z, scal0, -p.w) - m0);
        float e1a = EXP2F(fmaf(p.x, scal1, -p.y) - m1);
        float e1b = EXP2F(fmaf(p.z, scal1, -p.w) - m1);
        se0a += e0a; sd0a = fmaf(e0a, p.x, sd0a);
        se0b += e0b; sd0b = fmaf(e0b, p.z, sd0b);
        se1a += e1a; sd1a = fmaf(e1a, p.x, sd1a);
        se1b += e1b; sd1b = fmaf(e1b, p.z, sd1b);
    }
    float xs0 = (sd0a + sd0b) / (se0a + se0b);
    float xs1 = (sd1a + sd1b) / (se1a + se1b);

    int c = c0 + wid;
    const float* pw = pool_w + c * 21;
    float part = xs0 * pool_weight(pw, l) + xs1 * pool_weight(pw, l + 64);
    #pragma unroll
    for (int off = 32; off > 0; off >>= 1)
        part += __shfl_xor(part, off);
    if (l == 0) pooled[b * 256 + c] = part;

    // ---- completion gate ----
    __syncthreads();
    if (tid == 0) {
        __threadfence();
        __hip_atomic_fetch_add(cnt, 1u, __ATOMIC_RELEASE,
                               __HIP_MEMORY_SCOPE_AGENT);
    }
    if (blk >= 16) return;

    if (tid == 0) {
        while (__hip_atomic_load(cnt, __ATOMIC_RELAXED,
                                 __HIP_MEMORY_SCOPE_AGENT) < (unsigned)NBLK)
            __builtin_amdgcn_s_sleep(8);
        (void)__hip_atomic_load(cnt, __ATOMIC_ACQUIRE,
                                __HIP_MEMORY_SCOPE_AGENT);
    }
    __syncthreads();
    __threadfence();

    // ---- MLP tail for batch bt = blk ----
    int bt = blk;
    za[tid] = pooled[bt * 256 + tid];
    __syncthreads();
    {   // lin1 + relu -> zb
        float acc = L1b[tid];
        const float* wr = L1w + tid * 256;
        #pragma unroll 8
        for (int k = 0; k < 256; k += 4) {
            float4 wv = *(const float4*)(wr + k);
            float4 iv = *(const float4*)(&za[k]);
            acc = fmaf(wv.x, iv.x, acc); acc = fmaf(wv.y, iv.y, acc);
            acc = fmaf(wv.z, iv.z, acc); acc = fmaf(wv.w, iv.w, acc);
        }
        zb[tid] = fmaxf(acc, 0.f);
    }
    __syncthreads();
    {   // lin2 -> za
        float acc = L2b[tid];
        const float* wr = L2w + tid * 256;
        #pragma unroll 8
        for (int k = 0; k < 256; k += 4) {
            float4 wv = *(const float4*)(wr + k);
            float4 iv = *(const float4*)(&zb[k]);
            acc = fmaf(wv.x, iv.x, acc); acc = fmaf(wv.y, iv.y, acc);
            acc = fmaf(wv.z, iv.z, acc); acc = fmaf(wv.w, iv.w, acc);
        }
        za[tid] = acc;
    }
    __syncthreads();
    {   // cls1 + relu -> zb
        float acc = C1b[tid];
        const float* wr = C1w + tid * 256;
        #pragma unroll 8
        for (int k = 0; k < 256; k += 4) {
            float4 wv = *(const float4*)(wr + k);
            float4 iv = *(const float4*)(&za[k]);
            acc = fmaf(wv.x, iv.x, acc); acc = fmaf(wv.y, iv.y, acc);
            acc = fmaf(wv.z, iv.z, acc); acc = fmaf(wv.w, iv.w, acc);
        }
        zb[tid] = fmaxf(acc, 0.f);
    }
    __syncthreads();
    if (tid < 160) {   // cls2: 10 outputs x 16 lanes
        int o = tid >> 4, kk = tid & 15;
        const float* wr = C2w + o * 256;
        float pp = 0.f;
        #pragma unroll
        for (int k = kk * 16; k < kk * 16 + 16; k++)
            pp = fmaf(zb[k], wr[k], pp);
        pp += __shfl_down(pp, 8, 16);
        pp += __shfl_down(pp, 4, 16);
        pp += __shfl_down(pp, 2, 16);
        pp += __shfl_down(pp, 1, 16);
        if (kk == 0) out[bt * 10 + o] = pp + C2b[o];
    }
}

// ---------------------------------------------------------------------------
extern "C" void kernel_launch(void* const* d_in, const int* in_sizes, int n_in,
                              void* d_out, int out_size, void* d_ws, size_t ws_size,
                              hipStream_t stream)
{
    (void)in_sizes; (void)n_in; (void)out_size; (void)ws_size;
    const float* x       = (const float*)d_in[0];
    const float* conv1_w = (const float*)d_in[1];
    const float* conv1_b = (const float*)d_in[2];
    const float* conv2_w = (const float*)d_in[3];
    const float* conv2_b = (const float*)d_in[4];
    const float* pool_w  = (const float*)d_in[5];
    const float* lin1_w  = (const float*)d_in[6];
    const float* lin1_b  = (const float*)d_in[7];
    const float* lin2_w  = (const float*)d_in[8];
    const float* lin2_b  = (const float*)d_in[9];
    const float* cls1_w  = (const float*)d_in[10];
    const float* cls1_b  = (const float*)d_in[11];
    const float* cls2_w  = (const float*)d_in[12];
    const float* cls2_b  = (const float*)d_in[13];
    float* out = (float*)d_out;

    float*    pooled = (float*)d_ws;                 // 4096 floats
    unsigned* cnt    = (unsigned*)((float*)d_ws + 4096);

    hipMemsetAsync(cnt, 0, sizeof(unsigned), stream);
    fused_all<<<NBLK, 256, 0, stream>>>(
        x, conv1_w, conv1_b, conv2_w, conv2_b, pool_w,
        lin1_w, lin1_b, lin2_w, lin2_b, cls1_w, cls1_b, cls2_w, cls2_b,
        pooled, cnt, out);
}

// Round 8
// 64.694 us; speedup vs baseline: 4.5256x; 1.3259x over previous
//
#include <hip/hip_runtime.h>
#include <math.h>

// IN_C=3, DIM=256, OUT_C=256, N_PIECES=20, BATCH=16, SET_N=128

#if __has_builtin(__builtin_amdgcn_exp2f)
#define EXP2F(x) __builtin_amdgcn_exp2f(x)
#else
#define EXP2F(x) exp2f(x)
#endif

__device__ __forceinline__ float pool_weight(const float* __restrict__ pw, int j)
{
    float ratio = (float)j / 127.0f;
    float idx_f = 20.0f * ratio;
    int idx = (int)idx_f;
    float frac = idx_f - (float)idx;
    int idx2 = idx + 1 > 20 ? 20 : idx + 1;
    return (1.0f - frac) * pw[idx] + frac * pw[idx2];
}

// ---------------------------------------------------------------------------
// K1: conv1+conv2+fspool, wave-local, NO gate, NO fences (R7 phases verbatim).
// 1024 blocks x 256 thr (4 waves). Block = (b, 4-channel group).
// ---------------------------------------------------------------------------
__global__ __launch_bounds__(256) void conv_pool_kernel(
    const float* __restrict__ x,   const float* __restrict__ w1,
    const float* __restrict__ b1,  const float* __restrict__ W2,
    const float* __restrict__ b2,  const float* __restrict__ pool_w,
    float* __restrict__ pooled)
{
    const float LOG2E = 1.4426950408889634f;
    __shared__ float4 xa4[128];      // (x0,x1,x2,0) per n            2 KB
    __shared__ float4 w1p[256];      // (w1[k,0..2], b1[k])           4 KB
    __shared__ float  Ast[4][32];    // W2 sub-tile [d-local][k]      0.5 KB
    __shared__ float2 Bsp[32][65];   // relu(conv1) pairs (n, n+64)   16.6 KB
    __shared__ float2 sbp[4][128];   // (s_i, B_i*log2e) per row      4 KB

    int tid = threadIdx.x;
    int blk = blockIdx.x;
    int b   = blk >> 6;              // batch 0..15
    int c0  = (blk & 63) << 2;       // 4-row channel group

    // one-time staging
    w1p[tid] = make_float4(w1[tid*3], w1[tid*3+1], w1[tid*3+2], b1[tid]);
    if (tid < 128)
        xa4[tid] = make_float4(x[b*384 + tid], x[b*384 + 128 + tid],
                               x[b*384 + 256 + tid], 0.0f);
    __syncthreads();

    int wid = tid >> 6, l = tid & 63;
    int krel = tid & 31, p0 = (tid >> 5) * 8;
    float acc0 = 0.f, acc1 = 0.f;

    for (int k0 = 0; k0 < 256; k0 += 32) {
        if (tid < 128)
            Ast[tid >> 5][tid & 31] =
                W2[(c0 + (tid >> 5)) * 256 + k0 + (tid & 31)];
        {
            float4 wv = w1p[k0 + krel];
            #pragma unroll
            for (int i = 0; i < 8; i++) {
                int p = p0 + i;
                float4 xlo = xa4[p];
                float4 xhi = xa4[p + 64];
                float h0 = fmaf(wv.x, xlo.x, fmaf(wv.y, xlo.y,
                           fmaf(wv.z, xlo.z, wv.w)));
                float h1 = fmaf(wv.x, xhi.x, fmaf(wv.y, xhi.y,
                           fmaf(wv.z, xhi.z, wv.w)));
                Bsp[krel][p] = make_float2(fmaxf(h0, 0.f), fmaxf(h1, 0.f));
            }
        }
        __syncthreads();
        float4 a4[8];
        #pragma unroll
        for (int q = 0; q < 8; q++)
            a4[q] = *(const float4*)&Ast[wid][q * 4];
        #pragma unroll
        for (int kk = 0; kk < 32; kk++) {
            float a = ((const float*)a4)[kk];
            float2 bv = Bsp[kk][l];
            acc0 = fmaf(a, bv.x, acc0);
            acc1 = fmaf(a, bv.y, acc1);
        }
        __syncthreads();
    }

    // ---- fspool (wave-local; wave wid owns row c0+wid) ----
    float bias = b2[c0 + wid];
    float s0 = acc0 + bias, s1 = acc1 + bias;
    sbp[wid][l]      = make_float2(s0, 0.f);
    sbp[wid][l + 64] = make_float2(s1, 0.f);

    float a0 = 0.f, a1 = 0.f, g0 = 0.f, g1 = 0.f;
    #pragma unroll 8
    for (int j = 0; j < 128; j += 2) {
        float4 p = *(const float4*)&sbp[wid][j];
        a0 += fabsf(s0 - p.x); a1 += fabsf(s0 - p.z);
        g0 += fabsf(s1 - p.x); g1 += fabsf(s1 - p.z);
    }
    sbp[wid][l].y      = (a0 + a1) * LOG2E;
    sbp[wid][l + 64].y = (g0 + g1) * LOG2E;

    float scal0 = (float)(127 - 2 * l) * LOG2E;
    float scal1 = (float)(-1 - 2 * l) * LOG2E;
    float m00 = -1e30f, m01 = -1e30f, m10 = -1e30f, m11 = -1e30f;
    #pragma unroll 8
    for (int i = 0; i < 128; i += 2) {
        float4 p = *(const float4*)&sbp[wid][i];
        m00 = fmaxf(m00, fmaf(p.x, scal0, -p.y));
        m01 = fmaxf(m01, fmaf(p.z, scal0, -p.w));
        m10 = fmaxf(m10, fmaf(p.x, scal1, -p.y));
        m11 = fmaxf(m11, fmaf(p.z, scal1, -p.w));
    }
    float m0 = fmaxf(m00, m01), m1 = fmaxf(m10, m11);

    float se0a = 0.f, se0b = 0.f, sd0a = 0.f, sd0b = 0.f;
    float se1a = 0.f, se1b = 0.f, sd1a = 0.f, sd1b = 0.f;
    #pragma unroll 4
    for (int i = 0; i < 128; i += 2) {
        float4 p = *(const float4*)&sbp[wid][i];
        float e0a = EXP2F(fmaf(p.x, scal0, -p.y) - m0);
        float e0b = EXP2F(fmaf(p.z, scal0, -p.w) - m0);
        float e1a = EXP2F(fmaf(p.x, scal1, -p.y) - m1);
        float e1b = EXP2F(fmaf(p.z, scal1, -p.w) - m1);
        se0a += e0a; sd0a = fmaf(e0a, p.x, sd0a);
        se0b += e0b; sd0b = fmaf(e0b, p.z, sd0b);
        se1a += e1a; sd1a = fmaf(e1a, p.x, sd1a);
        se1b += e1b; sd1b = fmaf(e1b, p.z, sd1b);
    }
    float xs0 = (sd0a + sd0b) / (se0a + se0b);
    float xs1 = (sd1a + sd1b) / (se1a + se1b);

    int c = c0 + wid;
    const float* pw = pool_w + c * 21;
    float part = xs0 * pool_weight(pw, l) + xs1 * pool_weight(pw, l + 64);
    #pragma unroll
    for (int off = 32; off > 0; off >>= 1)
        part += __shfl_xor(part, off);
    if (l == 0) pooled[b * 256 + c] = part;
}

// ---------------------------------------------------------------------------
// K2: MLP tail. 16 blocks x 256 thr, one block per batch row (R7 tail verbatim).
// ---------------------------------------------------------------------------
__global__ __launch_bounds__(256) void tail_kernel(
    const float* __restrict__ pooled,
    const float* __restrict__ L1w, const float* __restrict__ L1b,
    const float* __restrict__ L2w, const float* __restrict__ L2b,
    const float* __restrict__ C1w, const float* __restrict__ C1b,
    const float* __restrict__ C2w, const float* __restrict__ C2b,
    float* __restrict__ out)
{
    __shared__ float za[256], zb[256];
    int bt = blockIdx.x, tid = threadIdx.x;
    za[tid] = pooled[bt * 256 + tid];
    __syncthreads();
    {   // lin1 + relu -> zb
        float acc = L1b[tid];
        const float* wr = L1w + tid * 256;
        #pragma unroll 8
        for (int k = 0; k < 256; k += 4) {
            float4 wv = *(const float4*)(wr + k);
            float4 iv = *(const float4*)(&za[k]);
            acc = fmaf(wv.x, iv.x, acc); acc = fmaf(wv.y, iv.y, acc);
            acc = fmaf(wv.z, iv.z, acc); acc = fmaf(wv.w, iv.w, acc);
        }
        zb[tid] = fmaxf(acc, 0.f);
    }
    __syncthreads();
    {   // lin2 -> za
        float acc = L2b[tid];
        const float* wr = L2w + tid * 256;
        #pragma unroll 8
        for (int k = 0; k < 256; k += 4) {
            float4 wv = *(const float4*)(wr + k);
            float4 iv = *(const float4*)(&zb[k]);
            acc = fmaf(wv.x, iv.x, acc); acc = fmaf(wv.y, iv.y, acc);
            acc = fmaf(wv.z, iv.z, acc); acc = fmaf(wv.w, iv.w, acc);
        }
        za[tid] = acc;
    }
    __syncthreads();
    {   // cls1 + relu -> zb
        float acc = C1b[tid];
        const float* wr = C1w + tid * 256;
        #pragma unroll 8
        for (int k = 0; k < 256; k += 4) {
            float4 wv = *(const float4*)(wr + k);
            float4 iv = *(const float4*)(&za[k]);
            acc = fmaf(wv.x, iv.x, acc); acc = fmaf(wv.y, iv.y, acc);
            acc = fmaf(wv.z, iv.z, acc); acc = fmaf(wv.w, iv.w, acc);
        }
        zb[tid] = fmaxf(acc, 0.f);
    }
    __syncthreads();
    if (tid < 160) {   // cls2: 10 outputs x 16 lanes
        int o = tid >> 4, kk = tid & 15;
        const float* wr = C2w + o * 256;
        float pp = 0.f;
        #pragma unroll
        for (int k = kk * 16; k < kk * 16 + 16; k++)
            pp = fmaf(zb[k], wr[k], pp);
        pp += __shfl_down(pp, 8, 16);
        pp += __shfl_down(pp, 4, 16);
        pp += __shfl_down(pp, 2, 16);
        pp += __shfl_down(pp, 1, 16);
        if (kk == 0) out[bt * 10 + o] = pp + C2b[o];
    }
}

// ---------------------------------------------------------------------------
extern "C" void kernel_launch(void* const* d_in, const int* in_sizes, int n_in,
                              void* d_out, int out_size, void* d_ws, size_t ws_size,
                              hipStream_t stream)
{
    (void)in_sizes; (void)n_in; (void)out_size; (void)ws_size;
    const float* x       = (const float*)d_in[0];
    const float* conv1_w = (const float*)d_in[1];
    const float* conv1_b = (const float*)d_in[2];
    const float* conv2_w = (const float*)d_in[3];
    const float* conv2_b = (const float*)d_in[4];
    const float* pool_w  = (const float*)d_in[5];
    const float* lin1_w  = (const float*)d_in[6];
    const float* lin1_b  = (const float*)d_in[7];
    const float* lin2_w  = (const float*)d_in[8];
    const float* lin2_b  = (const float*)d_in[9];
    const float* cls1_w  = (const float*)d_in[10];
    const float* cls1_b  = (const float*)d_in[11];
    const float* cls2_w  = (const float*)d_in[12];
    const float* cls2_b  = (const float*)d_in[13];
    float* out = (float*)d_out;

    float* pooled = (float*)d_ws;        // 4096 floats

    conv_pool_kernel<<<1024, 256, 0, stream>>>(
        x, conv1_w, conv1_b, conv2_w, conv2_b, pool_w, pooled);
    tail_kernel<<<16, 256, 0, stream>>>(pooled,
        lin1_w, lin1_b, lin2_w, lin2_b, cls1_w, cls1_b, cls2_w, cls2_b, out);
}

// Round 9
// 62.612 us; speedup vs baseline: 4.6762x; 1.0333x over previous
//
#include <hip/hip_runtime.h>
#include <math.h>

// IN_C=3, DIM=256, OUT_C=256, N_PIECES=20, BATCH=16, SET_N=128

#if __has_builtin(__builtin_amdgcn_exp2f)
#define EXP2F(x) __builtin_amdgcn_exp2f(x)
#else
#define EXP2F(x) exp2f(x)
#endif

__device__ __forceinline__ float pool_weight(const float* __restrict__ pw, int j)
{
    float ratio = (float)j / 127.0f;
    float idx_f = 20.0f * ratio;
    int idx = (int)idx_f;
    float frac = idx_f - (float)idx;
    int idx2 = idx + 1 > 20 ? 20 : idx + 1;
    return (1.0f - frac) * pw[idx] + frac * pw[idx2];
}

// one online-softmax step (log2 domain): v = s*scal - B
#define OSTEP(sv, bv, scal, m, se, sd)                      \
    {                                                       \
        float v_  = fmaf((sv), (scal), -(bv));              \
        float mn_ = fmaxf((m), v_);                         \
        float sc_ = EXP2F((m) - mn_);                       \
        float e_  = EXP2F(v_ - mn_);                        \
        (se) = fmaf((se), sc_, e_);                         \
        (sd) = fmaf((sd), sc_, e_ * (sv));                  \
        (m)  = mn_;                                         \
    }

// ---------------------------------------------------------------------------
// K1: conv1+conv2+fspool. 1024 blocks x 256 thr (4 waves). Block=(b, 4 rows).
// LDS-instruction-minimized vs R8:
//  - x held in 12 regs/thread (no xa4 LDS re-reads)
//  - staging: thread = 4 k x 4 n, 4 b128 writes/step
//  - fspool: Bsum reads compact s-array (32 b128), softmax is ONLINE
//    single-pass (64 b128) -- no separate max pass.
// ---------------------------------------------------------------------------
__global__ __launch_bounds__(256) void conv_pool_kernel(
    const float* __restrict__ x,   const float* __restrict__ w1,
    const float* __restrict__ b1,  const float* __restrict__ W2,
    const float* __restrict__ b2,  const float* __restrict__ pool_w,
    float* __restrict__ pooled)
{
    const float LOG2E = 1.4426950408889634f;
    __shared__ float4 w1p[256];      // (w1[k,0..2], b1[k])          4 KB
    __shared__ float  Ast[4][32];    // W2 sub-tile [d-local][k]     0.5 KB
    __shared__ float2 Bsp[32][66];   // relu(conv1) pairs (n, n+64)  16.9 KB
    __shared__ float  ss[4][128];    // s values per row             2 KB
    __shared__ float  bb[4][128];    // B*log2e per row              2 KB

    int tid = threadIdx.x;
    int blk = blockIdx.x;
    int b   = blk >> 6;              // batch 0..15
    int c0  = (blk & 63) << 2;       // 4-row channel group

    int wid = tid >> 6, l = tid & 63;
    int ng  = tid & 31;              // n-pair base group
    int kg  = tid >> 5;              // 0..7 -> stages krel = kg*4..+3
    int n0  = ng * 2;

    // one-time staging: w1 params to LDS, own x columns to registers
    w1p[tid] = make_float4(w1[tid*3], w1[tid*3+1], w1[tid*3+2], b1[tid]);
    const float* xb = x + b * 384;
    float x00 = xb[n0],          x01 = xb[n0 + 1];
    float x0a = xb[n0 + 64],     x0b = xb[n0 + 65];
    float x10 = xb[128 + n0],    x11 = xb[128 + n0 + 1];
    float x1a = xb[128 + n0 + 64], x1b = xb[128 + n0 + 65];
    float x20 = xb[256 + n0],    x21 = xb[256 + n0 + 1];
    float x2a = xb[256 + n0 + 64], x2b = xb[256 + n0 + 65];
    __syncthreads();

    float acc0 = 0.f, acc1 = 0.f;

    for (int k0 = 0; k0 < 256; k0 += 32) {
        if (tid < 128)
            Ast[tid >> 5][tid & 31] =
                W2[(c0 + (tid >> 5)) * 256 + k0 + (tid & 31)];
        #pragma unroll
        for (int q = 0; q < 4; q++) {
            int krel = kg * 4 + q;
            float4 wv = w1p[k0 + krel];
            float h0 = fmaxf(fmaf(wv.x,x00, fmaf(wv.y,x10, fmaf(wv.z,x20, wv.w))), 0.f);
            float h1 = fmaxf(fmaf(wv.x,x01, fmaf(wv.y,x11, fmaf(wv.z,x21, wv.w))), 0.f);
            float ha = fmaxf(fmaf(wv.x,x0a, fmaf(wv.y,x1a, fmaf(wv.z,x2a, wv.w))), 0.f);
            float hb = fmaxf(fmaf(wv.x,x0b, fmaf(wv.y,x1b, fmaf(wv.z,x2b, wv.w))), 0.f);
            // Bsp[krel][n0] = (h_n0, h_n0+64); Bsp[krel][n0+1] = (h_n0+1, h_n0+65)
            *(float4*)&Bsp[krel][n0] = make_float4(h0, ha, h1, hb);
        }
        __syncthreads();
        float4 a4[8];
        #pragma unroll
        for (int q = 0; q < 8; q++)
            a4[q] = *(const float4*)&Ast[wid][q * 4];
        #pragma unroll
        for (int kk = 0; kk < 32; kk++) {
            float a = ((const float*)a4)[kk];
            float2 bv = Bsp[kk][l];
            acc0 = fmaf(a, bv.x, acc0);
            acc1 = fmaf(a, bv.y, acc1);
        }
        __syncthreads();
    }

    // ---- fspool (wave-local; wave wid owns row c0+wid) ----
    float bias = b2[c0 + wid];
    float s0 = acc0 + bias, s1 = acc1 + bias;
    ss[wid][l]      = s0;
    ss[wid][l + 64] = s1;

    // Bsum for own i0=l, i1=l+64 (reads compact s-array)
    float a0=0,a1=0,a2=0,a3=0, g0=0,g1=0,g2=0,g3=0;
    #pragma unroll 8
    for (int j = 0; j < 128; j += 4) {
        float4 s4 = *(const float4*)&ss[wid][j];
        a0 += fabsf(s0 - s4.x); a1 += fabsf(s0 - s4.y);
        a2 += fabsf(s0 - s4.z); a3 += fabsf(s0 - s4.w);
        g0 += fabsf(s1 - s4.x); g1 += fabsf(s1 - s4.y);
        g2 += fabsf(s1 - s4.z); g3 += fabsf(s1 - s4.w);
    }
    bb[wid][l]      = ((a0+a1)+(a2+a3)) * LOG2E;
    bb[wid][l + 64] = ((g0+g1)+(g2+g3)) * LOG2E;

    // online softmax for j0=l, j1=l+64; 2 interleaved chains per j
    float scal0 = (float)(127 - 2 * l) * LOG2E;
    float scal1 = (float)(-1 - 2 * l) * LOG2E;
    float mA0=-1e30f, mB0=-1e30f, mA1=-1e30f, mB1=-1e30f;
    float seA0=0,seB0=0,sdA0=0,sdB0=0;
    float seA1=0,seB1=0,sdA1=0,sdB1=0;
    #pragma unroll 4
    for (int i = 0; i < 128; i += 4) {
        float4 s4 = *(const float4*)&ss[wid][i];
        float4 b4 = *(const float4*)&bb[wid][i];
        OSTEP(s4.x, b4.x, scal0, mA0, seA0, sdA0);
        OSTEP(s4.y, b4.y, scal0, mB0, seB0, sdB0);
        OSTEP(s4.z, b4.z, scal0, mA0, seA0, sdA0);
        OSTEP(s4.w, b4.w, scal0, mB0, seB0, sdB0);
        OSTEP(s4.x, b4.x, scal1, mA1, seA1, sdA1);
        OSTEP(s4.y, b4.y, scal1, mB1, seB1, sdB1);
        OSTEP(s4.z, b4.z, scal1, mA1, seA1, sdA1);
        OSTEP(s4.w, b4.w, scal1, mB1, seB1, sdB1);
    }
    float m0  = fmaxf(mA0, mB0);
    float scA = EXP2F(mA0 - m0), scB = EXP2F(mB0 - m0);
    float xs0 = (sdA0 * scA + sdB0 * scB) / (seA0 * scA + seB0 * scB);
    float m1  = fmaxf(mA1, mB1);
    float tA  = EXP2F(mA1 - m1), tB = EXP2F(mB1 - m1);
    float xs1 = (sdA1 * tA + sdB1 * tB) / (seA1 * tA + seB1 * tB);

    int c = c0 + wid;
    const float* pw = pool_w + c * 21;
    float part = xs0 * pool_weight(pw, l) + xs1 * pool_weight(pw, l + 64);
    #pragma unroll
    for (int off = 32; off > 0; off >>= 1)
        part += __shfl_xor(part, off);
    if (l == 0) pooled[b * 256 + c] = part;
}

// ---------------------------------------------------------------------------
// K2: MLP tail. 16 blocks x 512 thr: dense layers with split-K=2 + shfl pair
// reduce (R6-verified pattern).
// ---------------------------------------------------------------------------
__device__ __forceinline__ void dense512(
    const float* __restrict__ W, const float* __restrict__ Bv,
    const float* in_lds, float* out_lds, int tid, bool do_relu)
{
    int o = tid >> 1, p = tid & 1;
    const float* wr = W + o * 256 + p * 128;
    const float* ir = in_lds + p * 128;
    float acc = 0.f;
    #pragma unroll
    for (int k = 0; k < 128; k += 4) {
        float4 wv = *(const float4*)(wr + k);
        float4 iv = *(const float4*)(ir + k);
        acc = fmaf(wv.x, iv.x, acc); acc = fmaf(wv.y, iv.y, acc);
        acc = fmaf(wv.z, iv.z, acc); acc = fmaf(wv.w, iv.w, acc);
    }
    acc += __shfl_xor(acc, 1);
    if (p == 0) {
        acc += Bv[o];
        out_lds[o] = do_relu ? fmaxf(acc, 0.f) : acc;
    }
}

__global__ __launch_bounds__(512) void tail_kernel(
    const float* __restrict__ pooled,
    const float* __restrict__ L1w, const float* __restrict__ L1b,
    const float* __restrict__ L2w, const float* __restrict__ L2b,
    const float* __restrict__ C1w, const float* __restrict__ C1b,
    const float* __restrict__ C2w, const float* __restrict__ C2b,
    float* __restrict__ out)
{
    __shared__ float za[256], zb[256];
    int bt = blockIdx.x, tid = threadIdx.x;
    if (tid < 256) za[tid] = pooled[bt * 256 + tid];
    __syncthreads();
    dense512(L1w, L1b, za, zb, tid, true);
    __syncthreads();
    dense512(L2w, L2b, zb, za, tid, false);
    __syncthreads();
    dense512(C1w, C1b, za, zb, tid, true);
    __syncthreads();
    if (tid < 320) {   // cls2: 10 outputs x 32 lanes, 8 k each
        int o = tid >> 5, kb = tid & 31;
        const float* wr = C2w + o * 256 + kb * 8;
        const float* ir = zb + kb * 8;
        float4 w0 = *(const float4*)(wr);
        float4 w1v = *(const float4*)(wr + 4);
        float4 i0 = *(const float4*)(ir);
        float4 i1 = *(const float4*)(ir + 4);
        float p = fmaf(w0.x,i0.x, fmaf(w0.y,i0.y, fmaf(w0.z,i0.z,
                  fmaf(w0.w,i0.w, fmaf(w1v.x,i1.x, fmaf(w1v.y,i1.y,
                  fmaf(w1v.z,i1.z, w1v.w*i1.w)))))));
        #pragma unroll
        for (int off = 16; off > 0; off >>= 1)
            p += __shfl_xor(p, off, 32);
        if (kb == 0) out[bt * 10 + o] = p + C2b[o];
    }
}

// ---------------------------------------------------------------------------
extern "C" void kernel_launch(void* const* d_in, const int* in_sizes, int n_in,
                              void* d_out, int out_size, void* d_ws, size_t ws_size,
                              hipStream_t stream)
{
    (void)in_sizes; (void)n_in; (void)out_size; (void)ws_size;
    const float* x       = (const float*)d_in[0];
    const float* conv1_w = (const float*)d_in[1];
    const float* conv1_b = (const float*)d_in[2];
    const float* conv2_w = (const float*)d_in[3];
    const float* conv2_b = (const float*)d_in[4];
    const float* pool_w  = (const float*)d_in[5];
    const float* lin1_w  = (const float*)d_in[6];
    const float* lin1_b  = (const float*)d_in[7];
    const float* lin2_w  = (const float*)d_in[8];
    const float* lin2_b  = (const float*)d_in[9];
    const float* cls1_w  = (const float*)d_in[10];
    const float* cls1_b  = (const float*)d_in[11];
    const float* cls2_w  = (const float*)d_in[12];
    const float* cls2_b  = (const float*)d_in[13];
    float* out = (float*)d_out;

    float* pooled = (float*)d_ws;        // 4096 floats

    conv_pool_kernel<<<1024, 256, 0, stream>>>(
        x, conv1_w, conv1_b, conv2_w, conv2_b, pool_w, pooled);
    tail_kernel<<<16, 512, 0, stream>>>(pooled,
        lin1_w, lin1_b, lin2_w, lin2_b, cls1_w, cls1_b, cls2_w, cls2_b, out);
}